// Round 5
// baseline (45.451 us; speedup 1.0000x reference)
//
#include <hip/hip_runtime.h>

typedef short bf16x8 __attribute__((ext_vector_type(8)));
typedef float f32x4  __attribute__((ext_vector_type(4)));

static constexpr int KH = 15, KW = 15;
static constexpr int HI = 4096, WI = 4096;
static constexpr int HO = HI - KH + 1, WO = WI - KW + 1;   // 4082 x 4082
static constexpr int TM = 64, TN = 128;                    // output tile per block
static constexpr int LR   = TM + KH - 1;                   // 78 staged rows
static constexpr int LRA  = 80;                            // allocated rows (S4 touches rows 64..79; 78/79 never selected)
static constexpr int LC   = TN + 16;                       // 144 staged bf16 cols
static constexpr int LSTR = 152;                           // 304 B/row: 16B-aligned; 2-way bank alias max (free)
static constexpr int IPR  = LC / 4;                        // 36 float4 items per row

__device__ __forceinline__ unsigned int f2bf(float f) {
  unsigned int u = __builtin_bit_cast(unsigned int, f);
  return (u + 0x7FFFu + ((u >> 16) & 1u)) >> 16;
}

__device__ __forceinline__ unsigned int cvt_pk_bf16(float lo, float hi) {
  unsigned int r;
  asm("v_cvt_pk_bf16_f32 %0, %1, %2" : "=v"(r) : "v"(lo), "v"(hi));
  return r;
}

// row_ror:N within 16-lane rows: dst lane i <- src lane (i-N) mod 16
template<int CTRL>
__device__ __forceinline__ int4 dpp_ror(int4 s) {
  int4 r;
  r.x = __builtin_amdgcn_update_dpp(s.x, s.x, CTRL, 0xF, 0xF, false);
  r.y = __builtin_amdgcn_update_dpp(s.y, s.y, CTRL, 0xF, 0xF, false);
  r.z = __builtin_amdgcn_update_dpp(s.z, s.z, CTRL, 0xF, 0xF, false);
  r.w = __builtin_amdgcn_update_dpp(s.w, s.w, CTRL, 0xF, 0xF, false);
  return r;
}

__device__ __forceinline__ int4 sel4(bool c, int4 a, int4 b) {
  int4 r;
  r.x = c ? a.x : b.x;  r.y = c ? a.y : b.y;
  r.z = c ? a.z : b.z;  r.w = c ? a.w : b.w;
  return r;
}

__device__ __forceinline__ bf16x8 bc(int4 v) { return __builtin_bit_cast(bf16x8, v); }

#define MFMA(a, b, c) __builtin_amdgcn_mfma_f32_16x16x32_bf16((a), (b), (c), 0, 0, 0)

__global__ __launch_bounds__(512, 4)
void conv2d_dpp(const float* __restrict__ x, const float* __restrict__ w,
                const float* __restrict__ bias, float* __restrict__ out) {
  __shared__ unsigned short sx[LRA * LSTR];       // 24,320 B bf16 input tile
  __shared__ unsigned short btab[15 * 64 * 8];    // 15,360 B banded B-fragments

  const int tid  = threadIdx.x;
  const int row0 = blockIdx.y * TM;
  const int col0 = blockIdx.x * TN;

  // ---- banded weight fragments from global w: B_kh[p][j] = w[kh, p-j], 0<=p-j<15 ----
  for (int i = tid; i < 15 * 64; i += 512) {
    const int kh = i >> 6;
    const int l  = i & 63;
    const int j  = l & 15;
    const int p0 = (l >> 4) * 8;
    unsigned int d[4];
    #pragma unroll
    for (int t2 = 0; t2 < 4; ++t2) {
      const int idx0 = p0 + 2 * t2 - j;
      const int idx1 = idx0 + 1;
      const unsigned int b0 = (idx0 >= 0 && idx0 < KW) ? f2bf(w[kh * KW + idx0]) : 0u;
      const unsigned int b1 = (idx1 >= 0 && idx1 < KW) ? f2bf(w[kh * KW + idx1]) : 0u;
      d[t2] = b0 | (b1 << 16);
    }
    *(uint4*)&btab[i * 8] = make_uint4(d[0], d[1], d[2], d[3]);
  }

  // ---- stage 78 x 144 input tile as bf16 (zero-fill OOB halo) ----
  for (int i = tid; i < LR * IPR; i += 512) {
    const int r  = i / IPR;
    const int c4 = (i - r * IPR) * 4;
    const int gr = row0 + r;
    const int gc = col0 + c4;
    float4 v = make_float4(0.f, 0.f, 0.f, 0.f);
    if (gr < HI) {
      const float* p = &x[(long)gr * WI + gc];
      if (gc + 3 < WI) {
        v = *(const float4*)p;
      } else {
        if (gc + 0 < WI) v.x = p[0];
        if (gc + 1 < WI) v.y = p[1];
        if (gc + 2 < WI) v.z = p[2];
        if (gc + 3 < WI) v.w = p[3];
      }
    }
    *(uint2*)&sx[r * LSTR + c4] = make_uint2(cvt_pk_bf16(v.x, v.y), cvt_pk_bf16(v.z, v.w));
  }

  const float bs = bias[0];
  __syncthreads();

  // ---- per-wave setup: wave wv -> output cols [wv*16, wv*16+16) ----
  const int lane = tid & 63;
  const int wv   = tid >> 6;
  const int q    = lane & 15;                      // A-frag row id
  const int acol = wv * 16 + (lane >> 4) * 8;      // A-frag k-col base
  const unsigned short* sbase = &sx[q * LSTR + acol];
  const unsigned short* bbase = &btab[lane * 8];

  // 5 S-tiles: S_t = rows (lane&15)+16t of the wave's 32-col window
  int4 s0 = *(const int4*)(sbase + 0  * 16 * LSTR);
  int4 s1 = *(const int4*)(sbase + 1  * 16 * LSTR);
  int4 s2 = *(const int4*)(sbase + 2  * 16 * LSTR);
  int4 s3 = *(const int4*)(sbase + 3  * 16 * LSTR);
  int4 s4 = *(const int4*)(sbase + 4  * 16 * LSTR);

  f32x4 acc0 = {0.f,0.f,0.f,0.f}, acc1 = {0.f,0.f,0.f,0.f};
  f32x4 acc2 = {0.f,0.f,0.f,0.f}, acc3 = {0.f,0.f,0.f,0.f};

  // kh = 0: fragments are S_m directly
  {
    bf16x8 b = *(const bf16x8*)bbase;
    acc0 = MFMA(bc(s0), b, acc0);
    acc1 = MFMA(bc(s1), b, acc1);
    acc2 = MFMA(bc(s2), b, acc2);
    acc3 = MFMA(bc(s3), b, acc3);
  }

  // kh >= 1: frag(m,kh): lane q presents row q+16m+kh = row_ror:(16-kh) of S_m (no wrap) / S_{m+1} (wrap)
  #define KH_STEP(K)                                                          \
  {                                                                           \
    int4 r0 = dpp_ror<0x120 + 16 - (K)>(s0);                                  \
    int4 r1 = dpp_ror<0x120 + 16 - (K)>(s1);                                  \
    int4 r2 = dpp_ror<0x120 + 16 - (K)>(s2);                                  \
    int4 r3 = dpp_ror<0x120 + 16 - (K)>(s3);                                  \
    int4 r4 = dpp_ror<0x120 + 16 - (K)>(s4);                                  \
    const bool w_ = (q + (K)) >= 16;                                          \
    bf16x8 b = *(const bf16x8*)(bbase + (K) * 512);                           \
    acc0 = MFMA(bc(sel4(w_, r1, r0)), b, acc0);                               \
    acc1 = MFMA(bc(sel4(w_, r2, r1)), b, acc1);                               \
    acc2 = MFMA(bc(sel4(w_, r3, r2)), b, acc2);                               \
    acc3 = MFMA(bc(sel4(w_, r4, r3)), b, acc3);                               \
  }

  KH_STEP(1)  KH_STEP(2)  KH_STEP(3)  KH_STEP(4)  KH_STEP(5)
  KH_STEP(6)  KH_STEP(7)  KH_STEP(8)  KH_STEP(9)  KH_STEP(10)
  KH_STEP(11) KH_STEP(12) KH_STEP(13) KH_STEP(14)
  #undef KH_STEP

  // ---- epilogue: C/D layout col=lane&15, row=(lane>>4)*4+reg ----
  const int ocol = col0 + wv * 16 + q;
  if (ocol < WO) {
    const int orb = row0 + (lane >> 4) * 4;
    f32x4 av[4] = {acc0, acc1, acc2, acc3};
    #pragma unroll
    for (int m = 0; m < 4; ++m) {
      #pragma unroll
      for (int r = 0; r < 4; ++r) {
        const int orow = orb + 16 * m + r;
        if (orow < HO) out[(long)orow * WO + ocol] = av[m][r] + bs;
      }
    }
  }
}

extern "C" void kernel_launch(void* const* d_in, const int* in_sizes, int n_in,
                              void* d_out, int out_size, void* d_ws, size_t ws_size,
                              hipStream_t stream) {
  const float* x    = (const float*)d_in[0];
  const float* w    = (const float*)d_in[1];
  const float* bias = (const float*)d_in[2];
  float* out        = (float*)d_out;

  dim3 grid((WO + TN - 1) / TN, (HO + TM - 1) / TM);   // 32 x 64 = 2048 blocks
  conv2d_dpp<<<grid, dim3(512, 1, 1), 0, stream>>>(x, w, bias, out);
}

// Round 6
// 45.074 us; speedup vs baseline: 1.0084x; 1.0084x over previous
//
#include <hip/hip_runtime.h>

typedef short bf16x8 __attribute__((ext_vector_type(8)));
typedef float f32x16 __attribute__((ext_vector_type(16)));

static constexpr int KH = 15, KW = 15;
static constexpr int HI = 4096, WI = 4096;
static constexpr int HO = HI - KH + 1, WO = WI - KW + 1;   // 4082 x 4082
static constexpr int TM = 128, TN = 128;                   // output tile per block
static constexpr int LR   = TM + KH - 1;                   // 142 staged rows
static constexpr int LCS  = 148;                           // staged cols (37 float4; need 146)
static constexpr int LSTR = 152;                           // 304 B/row, 16B-aligned
static constexpr int IPR  = LCS / 4;                       // 37
static constexpr int ITEMS = LR * IPR;                     // 5254
static constexpr int NSLOT = 72;                           // B slot table: d' = 8kg - n + 31 + 16*sigma

__device__ __forceinline__ unsigned int f2bf(float f) {
  unsigned int u = __builtin_bit_cast(unsigned int, f);
  return (u + 0x7FFFu + ((u >> 16) & 1u)) >> 16;
}

__device__ __forceinline__ unsigned int cvt_pk_bf16(float lo, float hi) {
  unsigned int r;
  asm("v_cvt_pk_bf16_f32 %0, %1, %2" : "=v"(r) : "v"(lo), "v"(hi));
  return r;
}

#define MFMA32(a, b, c) __builtin_amdgcn_mfma_f32_32x32x16_bf16((a), (b), (c), 0, 0, 0)

__global__ __launch_bounds__(512, 4)
void conv2d_mfma32(const float* __restrict__ x, const float* __restrict__ w,
                   const float* __restrict__ bias, float* __restrict__ out) {
  __shared__ unsigned short sx[LR * LSTR];          // 43,168 B bf16 input tile
  __shared__ unsigned short btab[KH * NSLOT * 8];   // 17,280 B sliding-window weight slots

  const int tid = threadIdx.x;

  // XCD-aware swizzle (1024 blocks, 1024 % 8 == 0 -> simple bijective form)
  const int nwg  = gridDim.x * gridDim.y;
  const int cpx  = nwg >> 3;
  const int bid0 = blockIdx.y * gridDim.x + blockIdx.x;
  const int bid  = (bid0 % 8) * cpx + (bid0 / 8);
  const int row0 = (bid / 32) * TM;
  const int col0 = (bid % 32) * TN;

  // ---- B slot table: btab[kh][d'][t] = w[kh, d'-31+t] if in [0,15) else 0 ----
  // A lane later reads slot d' = 8*kg - n + 31 (+16*sigma via offset immediate):
  // value[t] = w[kh, 8*kg + t + 16*sigma - n]  == B_sigma[k][n] wrapped band.
  for (int i = tid; i < KH * NSLOT; i += 512) {
    const int kh = i / NSLOT;
    const int d  = i - kh * NSLOT;
    const int e0 = d - 31;
    unsigned int dw[4];
    #pragma unroll
    for (int t2 = 0; t2 < 4; ++t2) {
      const int c0 = e0 + 2 * t2;
      const int c1 = c0 + 1;
      const unsigned int b0 = (c0 >= 0 && c0 < KW) ? f2bf(w[kh * KW + c0]) : 0u;
      const unsigned int b1 = (c1 >= 0 && c1 < KW) ? f2bf(w[kh * KW + c1]) : 0u;
      dw[t2] = b0 | (b1 << 16);
    }
    *(uint4*)&btab[i * 8] = make_uint4(dw[0], dw[1], dw[2], dw[3]);
  }

  // ---- stage 142 x 148 input tile as bf16 (zero-fill OOB halo) ----
  for (int i = tid; i < ITEMS; i += 512) {
    const int r  = i / IPR;
    const int c4 = (i - r * IPR) * 4;
    const int gr = row0 + r;
    const int gc = col0 + c4;
    float4 v = make_float4(0.f, 0.f, 0.f, 0.f);
    if (gr < HI) {
      const float* p = &x[(long)gr * WI + gc];
      if (gc + 3 < WI) {
        v = *(const float4*)p;
      } else {
        if (gc + 0 < WI) v.x = p[0];
        if (gc + 1 < WI) v.y = p[1];
        if (gc + 2 < WI) v.z = p[2];
        if (gc + 3 < WI) v.w = p[3];
      }
    }
    *(uint2*)&sx[r * LSTR + c4] = make_uint2(cvt_pk_bf16(v.x, v.y), cvt_pk_bf16(v.z, v.w));
  }

  const float bs = bias[0];
  __syncthreads();

  // ---- per-wave setup: wave = (row-group g = wv>>1) x (col-half p = wv&1) ----
  // wave computes out rows [32g, 32g+32) x cols [64p, 64p+64) of the block tile,
  // as two 32x32 MFMA tiles sharing A granules (16-col slices).
  const int lane = tid & 63;
  const int wv   = tid >> 6;
  const int g    = wv >> 1;
  const int p    = wv & 1;
  const int n    = lane & 31;                 // out col within 32-tile / B n-index
  const int kg   = lane >> 5;                 // k-group (k = 8*kg + t)

  // A granule u (u=0..4): element = (32g + kh + i)*LSTR + 16*(4p+u) + 8kg, i = n
  const unsigned short* abase = &sx[(32 * g + n) * LSTR + 64 * p + 8 * kg];
  // B slots: one lane address, sigma and kh via offset immediates
  const unsigned short* bbase = &btab[(8 * kg - n + 31) * 8];

  f32x16 acc0, acc1;
  #pragma unroll
  for (int r = 0; r < 16; ++r) { acc0[r] = bs; acc1[r] = 0.f; }

  #pragma unroll
  for (int kh = 0; kh < KH; ++kh) {
    const unsigned short* ar = abase + kh * LSTR;
    const bf16x8 a0 = *(const bf16x8*)(ar + 0);
    const bf16x8 a1 = *(const bf16x8*)(ar + 16);
    const bf16x8 a2 = *(const bf16x8*)(ar + 32);
    const bf16x8 a3 = *(const bf16x8*)(ar + 48);
    const bf16x8 a4 = *(const bf16x8*)(ar + 64);
    const unsigned short* br = bbase + kh * (NSLOT * 8);
    const bf16x8 b0 = *(const bf16x8*)(br + 0);      // sigma 0
    const bf16x8 b1 = *(const bf16x8*)(br + 128);    // sigma 1 (+16 slots)
    const bf16x8 b2 = *(const bf16x8*)(br + 256);    // sigma 2 (+32 slots)
    acc0 = MFMA32(a0, b0, acc0);
    acc0 = MFMA32(a1, b1, acc0);
    acc0 = MFMA32(a2, b2, acc0);
    acc1 = MFMA32(a2, b0, acc1);
    acc1 = MFMA32(a3, b1, acc1);
    acc1 = MFMA32(a4, b2, acc1);
  }

  // ---- epilogue: 32x32 C/D layout col = lane&31, row = (reg&3) + 8*(reg>>2) + 4*kg ----
  const int oc  = col0 + 64 * p + n;
  const int orb = row0 + 32 * g + 4 * kg;
  #pragma unroll
  for (int r = 0; r < 16; ++r) {
    const int orow = orb + (r & 3) + 8 * (r >> 2);
    if (orow < HO) {
      if (oc < WO)      out[(long)orow * WO + oc]      = acc0[r];
      if (oc + 32 < WO) out[(long)orow * WO + oc + 32] = acc1[r] + bs;
    }
  }
}

extern "C" void kernel_launch(void* const* d_in, const int* in_sizes, int n_in,
                              void* d_out, int out_size, void* d_ws, size_t ws_size,
                              hipStream_t stream) {
  const float* x    = (const float*)d_in[0];
  const float* w    = (const float*)d_in[1];
  const float* bias = (const float*)d_in[2];
  float* out        = (float*)d_out;

  dim3 grid((WO + TN - 1) / TN, (HO + TM - 1) / TM);   // 32 x 32 = 1024 blocks
  conv2d_mfma32<<<grid, dim3(512, 1, 1), 0, stream>>>(x, w, bias, out);
}

// Round 7
// 39.544 us; speedup vs baseline: 1.1494x; 1.1398x over previous
//
#include <hip/hip_runtime.h>

typedef short bf16x8 __attribute__((ext_vector_type(8)));
typedef float f32x4  __attribute__((ext_vector_type(4)));

static constexpr int KH = 15, KW = 15;
static constexpr int HI = 4096, WI = 4096;
static constexpr int HO = HI - KH + 1, WO = WI - KW + 1;   // 4082 x 4082
static constexpr int TM = 64, TN = 128;                    // output tile
static constexpr int NT = 2;                               // tiles marched per block (vertical)
static constexpr int LR   = TM + KH - 1;                   // 78 staged rows
static constexpr int LC   = 144;                           // staged bf16 cols
static constexpr int LSTR = 152;                           // 304 B/row: 16B-aligned; benign 2-way banks
static constexpr int IPR   = LC / 4;                       // 36 float4 items/row
static constexpr int ITEMS = LR * IPR;                     // 2808
static constexpr int SITER = (ITEMS + 511) / 512;          // 6 per thread

__device__ __forceinline__ unsigned int f2bf(float f) {
  unsigned int u = __builtin_bit_cast(unsigned int, f);
  return (u + 0x7FFFu + ((u >> 16) & 1u)) >> 16;
}

__device__ __forceinline__ unsigned int cvt_pk_bf16(float lo, float hi) {
  unsigned int r;
  asm("v_cvt_pk_bf16_f32 %0, %1, %2" : "=v"(r) : "v"(lo), "v"(hi));
  return r;
}

__device__ __forceinline__ float4 load_item(const float* __restrict__ x,
                                            int row0, int col0, int it) {
  float4 v = make_float4(0.f, 0.f, 0.f, 0.f);
  if (it < ITEMS) {
    const int r  = it / IPR;
    const int c4 = (it - r * IPR) * 4;
    const int gr = row0 + r;
    const int gc = col0 + c4;
    if (gr < HI) {
      const float* p = &x[(long)gr * WI + gc];
      if (gc + 3 < WI) {
        v = *(const float4*)p;
      } else {
        if (gc + 0 < WI) v.x = p[0];
        if (gc + 1 < WI) v.y = p[1];
        if (gc + 2 < WI) v.z = p[2];
        if (gc + 3 < WI) v.w = p[3];
      }
    }
  }
  return v;
}

__device__ __forceinline__ void write_item(unsigned short* sx, int it, float4 v) {
  if (it < ITEMS) {
    const int r  = it / IPR;
    const int c4 = (it - r * IPR) * 4;
    *(uint2*)&sx[r * LSTR + c4] = make_uint2(cvt_pk_bf16(v.x, v.y), cvt_pk_bf16(v.z, v.w));
  }
}

#define MFMA16(a, b, c) __builtin_amdgcn_mfma_f32_16x16x32_bf16((a), (b), (c), 0, 0, 0)

__global__ __launch_bounds__(512, 4)
void conv2d_march(const float* __restrict__ x, const float* __restrict__ w,
                  const float* __restrict__ bias, float* __restrict__ out) {
  __shared__ unsigned short sx[LR * LSTR];        // 23,712 B single-buffer input tile
  __shared__ unsigned short btab[15 * 64 * 8];    // 15,360 B banded B-fragments

  const int tid   = threadIdx.x;
  const int col0  = blockIdx.x * TN;
  const int rbase = blockIdx.y * (NT * TM);

  // ---- banded weight fragments from global w: B_kh[p][j] = w[kh, p-j], 0<=p-j<15 ----
  for (int i = tid; i < 15 * 64; i += 512) {
    const int kh = i >> 6;
    const int l  = i & 63;
    const int j  = l & 15;
    const int p0 = (l >> 4) * 8;
    unsigned int d[4];
    #pragma unroll
    for (int t2 = 0; t2 < 4; ++t2) {
      const int idx0 = p0 + 2 * t2 - j;
      const int idx1 = idx0 + 1;
      const unsigned int b0 = (idx0 >= 0 && idx0 < KW) ? f2bf(w[kh * KW + idx0]) : 0u;
      const unsigned int b1 = (idx1 >= 0 && idx1 < KW) ? f2bf(w[kh * KW + idx1]) : 0u;
      d[t2] = b0 | (b1 << 16);
    }
    *(uint4*)&btab[i * 8] = make_uint4(d[0], d[1], d[2], d[3]);
  }

  // ---- stage tile 0 ----
  {
    float4 v0_[SITER];
    #pragma unroll
    for (int k = 0; k < SITER; ++k) v0_[k] = load_item(x, rbase, col0, tid + 512 * k);
    #pragma unroll
    for (int k = 0; k < SITER; ++k) write_item(sx, tid + 512 * k, v0_[k]);
  }
  const float bs = bias[0];
  __syncthreads();

  // ---- per-wave setup: wave wv -> output cols [wv*16, wv*16+16) ----
  const int lane = tid & 63;
  const int wv   = tid >> 6;
  const int q    = lane & 15;                      // A row id / out col id
  const unsigned short* abase = &sx[q * LSTR + wv * 16 + (lane >> 4) * 8];
  const unsigned short* bbase = &btab[lane * 8];
  const int ocol = col0 + wv * 16 + q;

  #pragma unroll
  for (int t = 0; t < NT; ++t) {
    const int row0 = rbase + t * TM;

    // issue next tile's loads; they land during the MFMA phase below
    float4 nv[SITER];
    if (t + 1 < NT) {
      #pragma unroll
      for (int k = 0; k < SITER; ++k)
        nv[k] = load_item(x, row0 + TM, col0, tid + 512 * k);
    }

    // compute current tile: per kh = 1 B-read + 4 A-reads + 4 MFMA
    f32x4 acc0 = {bs,bs,bs,bs}, acc1 = {bs,bs,bs,bs};
    f32x4 acc2 = {bs,bs,bs,bs}, acc3 = {bs,bs,bs,bs};
    __builtin_amdgcn_s_setprio(1);
    #pragma unroll
    for (int kh = 0; kh < 15; ++kh) {
      const bf16x8 b = *(const bf16x8*)(bbase + kh * 512);
      const unsigned short* ar = abase + kh * LSTR;
      acc0 = MFMA16(*(const bf16x8*)(ar + 0  * LSTR), b, acc0);
      acc1 = MFMA16(*(const bf16x8*)(ar + 16 * LSTR), b, acc1);
      acc2 = MFMA16(*(const bf16x8*)(ar + 32 * LSTR), b, acc2);
      acc3 = MFMA16(*(const bf16x8*)(ar + 48 * LSTR), b, acc3);
    }
    __builtin_amdgcn_s_setprio(0);

    // store: C/D layout col=lane&15, row=(lane>>4)*4+reg
    if (ocol < WO) {
      const int orb = row0 + (lane >> 4) * 4;
      const f32x4 av[4] = {acc0, acc1, acc2, acc3};
      #pragma unroll
      for (int m = 0; m < 4; ++m) {
        #pragma unroll
        for (int r = 0; r < 4; ++r) {
          const int orow = orb + 16 * m + r;
          if (orow < HO) out[(long)orow * WO + ocol] = av[m][r];
        }
      }
    }

    // rotate the single LDS buffer for the next tile
    if (t + 1 < NT) {
      __syncthreads();                              // everyone done reading sx
      #pragma unroll
      for (int k = 0; k < SITER; ++k) write_item(sx, tid + 512 * k, nv[k]);
      __syncthreads();                              // next tile visible
    }
  }
}

extern "C" void kernel_launch(void* const* d_in, const int* in_sizes, int n_in,
                              void* d_out, int out_size, void* d_ws, size_t ws_size,
                              hipStream_t stream) {
  const float* x    = (const float*)d_in[0];
  const float* w    = (const float*)d_in[1];
  const float* bias = (const float*)d_in[2];
  float* out        = (float*)d_out;

  dim3 grid((WO + TN - 1) / TN, (HO + NT * TM - 1) / (NT * TM));   // 32 x 32 = 1024 blocks, 4/CU resident
  conv2d_march<<<grid, dim3(512, 1, 1), 0, stream>>>(x, w, bias, out);
}